// Round 4
// baseline (304.533 us; speedup 1.0000x reference)
//
#include <hip/hip_runtime.h>
#include <math.h>

#define B_N 8
#define C_CH 128
#define H_IN 256
#define W_IN 256
#define HO 129
#define WO 129
#define SP (HO*WO)          // 16641
#define HIDDEN 11
#define NSTRIP 15
#define STRIP_H 9
#define MAXROWS 20
#define NGROUP 16
#define CPG 8               // channels per group
#define VITER 5             // ceil(STRIP_H*WO / 256)

__constant__ float c_lo[4] = {-0.12940952255126037f, 0.2241438680420134f,
                               0.8365163037378079f,  0.48296291314453416f};
__constant__ float c_hi[4] = {-0.48296291314453416f, 0.8365163037378079f,
                              -0.2241438680420134f, -0.12940952255126037f};

// -------- Kernel 1: fused DWT2 + per-channel & cross-channel reductions -----
// Block = (b, strip, group of 8 channels). Never materializes cA/cH.
__global__ __launch_bounds__(256) void dwt_fused_kernel(
    const float* __restrict__ x,
    float* __restrict__ psum, float* __restrict__ pmax,
    float* __restrict__ chpsum, float* __restrict__ chpmax)
{
  int bid   = blockIdx.x;                 // ((b*NSTRIP + strip)*NGROUP + g)
  int g     = bid & (NGROUP - 1);
  int tmp   = bid >> 4;
  int strip = tmp % NSTRIP;
  int b     = tmp / NSTRIP;

  int j0 = strip * STRIP_H;
  int j1 = min(j0 + STRIP_H, HO);
  int nj = j1 - j0;
  int rlo = max(0, 2*j0 - 2);
  int rhi = min(H_IN - 1, 2*j1 - 1);
  int nrows = rhi - rlo + 1;              // <= 20

  __shared__ float xs[MAXROWS * W_IN];    // 20 KB
  __shared__ float low[MAXROWS * WO];     // 10.3 KB
  __shared__ float s_psum[4 * CPG];
  __shared__ float s_pmax[4 * CPG];

  int tid = threadIdx.x;
  int tot2 = nj * WO;
  int tot4 = nrows * 64;

  float chs[VITER], chm[VITER];
  #pragma unroll
  for (int it = 0; it < VITER; ++it) { chs[it] = 0.f; chm[it] = -INFINITY; }

  // per-thread staging coords
  int prow = tid >> 6;        // base row for it-loop: row = prow + it*4
  int pc4  = tid & 63;

  // prefetch channel 0 of this group into registers
  float4 pf[VITER];
  {
    const float4* xp4 = reinterpret_cast<const float4*>(
        x + (size_t)(b * C_CH + g * CPG) * (H_IN * W_IN));
    #pragma unroll
    for (int it = 0; it < VITER; ++it) {
      int e = tid + it * 256;
      if (e < tot4) pf[it] = xp4[(rlo + prow + it * 4) * 64 + pc4];
    }
  }

  for (int ci = 0; ci < CPG; ++ci) {
    // write prefetched regs -> xs
    {
      float4* xs4 = reinterpret_cast<float4*>(xs);
      #pragma unroll
      for (int it = 0; it < VITER; ++it) {
        int e = tid + it * 256;
        if (e < tot4) xs4[e] = pf[it];
      }
    }
    __syncthreads();   // xs ready; also guards low (prev vpass done)

    // issue prefetch for next channel (hides HBM latency under h/v pass)
    if (ci + 1 < CPG) {
      const float4* xp4 = reinterpret_cast<const float4*>(
          x + (size_t)(b * C_CH + g * CPG + ci + 1) * (H_IN * W_IN));
      #pragma unroll
      for (int it = 0; it < VITER; ++it) {
        int e = tid + it * 256;
        if (e < tot4) pf[it] = xp4[(rlo + prow + it * 4) * 64 + pc4];
      }
    }

    // horizontal low-pass from LDS
    {
      int tot = nrows * WO;
      for (int e = tid; e < tot; e += 256) {
        int lr = e / WO;
        int j  = e - lr * WO;
        const float* row = xs + lr * W_IN;
        float acc = 0.f;
        int tb = 2*j + 1;
        #pragma unroll
        for (int m = 0; m < 4; ++m) {
          int t = tb - m;
          t = (t < 0) ? (-1 - t) : ((t > W_IN-1) ? (2*W_IN - 1 - t) : t);
          acc += c_lo[m] * row[t];
        }
        low[lr * WO + j] = acc;
      }
    }
    __syncthreads();   // low ready

    // vertical pass; accumulate per-channel and cross-channel stats
    float sumA = 0.f, maxH = -INFINITY;
    #pragma unroll
    for (int it = 0; it < VITER; ++it) {
      int e = tid + it * 256;
      if (e < tot2) {
        int lj  = e / WO;
        int col = e - lj * WO;
        int j   = j0 + lj;
        float a = 0.f, hv = 0.f;
        int tb = 2*j + 1;
        #pragma unroll
        for (int m = 0; m < 4; ++m) {
          int t = tb - m;
          t = (t < 0) ? (-1 - t) : ((t > H_IN-1) ? (2*H_IN - 1 - t) : t);
          float v = low[(t - rlo) * WO + col];
          a  += c_lo[m] * v;
          hv += c_hi[m] * v;
        }
        sumA += a;
        maxH = fmaxf(maxH, hv);
        chs[it] += a + hv;
        chm[it] = fmaxf(chm[it], fmaxf(a, hv));
      }
    }

    // per-channel wave reduction -> per-wave LDS slots (no barrier needed)
    for (int off = 32; off > 0; off >>= 1) {
      sumA += __shfl_down(sumA, off, 64);
      maxH = fmaxf(maxH, __shfl_down(maxH, off, 64));
    }
    if ((tid & 63) == 0) {
      int wave = tid >> 6;
      s_psum[wave * CPG + ci] = sumA;
      s_pmax[wave * CPG + ci] = maxH;
    }
    // next iteration's xs write is guarded by its __syncthreads()
  }

  __syncthreads();
  // finalize per-channel strip stats
  if (tid < CPG) {
    size_t bc = (size_t)(b * C_CH + g * CPG + tid);
    float ss = s_psum[0 * CPG + tid] + s_psum[1 * CPG + tid] +
               s_psum[2 * CPG + tid] + s_psum[3 * CPG + tid];
    float mm = fmaxf(fmaxf(s_pmax[0 * CPG + tid], s_pmax[1 * CPG + tid]),
                     fmaxf(s_pmax[2 * CPG + tid], s_pmax[3 * CPG + tid]));
    psum[bc * NSTRIP + strip] = ss;
    pmax[bc * NSTRIP + strip] = mm;
  }

  // write cross-channel group partials for this strip
  float* cps = chpsum + (size_t)(b * NGROUP + g) * SP;
  float* cpm = chpmax + (size_t)(b * NGROUP + g) * SP;
  #pragma unroll
  for (int it = 0; it < VITER; ++it) {
    int e = tid + it * 256;
    if (e < tot2) {
      int lj  = e / WO;
      int col = e - lj * WO;
      cps[(j0 + lj) * WO + col] = chs[it];
      cpm[(j0 + lj) * WO + col] = chm[it];
    }
  }
}

// -------- Kernel 2: combine group partials -> sa_in -------------------------
__global__ __launch_bounds__(256) void combine_kernel(
    const float* __restrict__ chpsum, const float* __restrict__ chpmax,
    float* __restrict__ sa_in)
{
  int b = blockIdx.y;
  int s = blockIdx.x * 256 + threadIdx.x;
  if (s >= SP) return;
  float sum = 0.f, mx = -INFINITY;
  #pragma unroll
  for (int gg = 0; gg < NGROUP; ++gg) {
    sum += chpsum[(size_t)(b * NGROUP + gg) * SP + s];
    mx = fmaxf(mx, chpmax[(size_t)(b * NGROUP + gg) * SP + s]);
  }
  sa_in[(size_t)b * 2 * SP + s]      = sum * (1.f / 256.f);
  sa_in[(size_t)b * 2 * SP + SP + s] = mx;
}

// -------- Kernel 3: channel-attention MLP -----------------------------------
__global__ __launch_bounds__(128) void mlp_kernel(
    const float* __restrict__ psum, const float* __restrict__ pmax,
    const float* __restrict__ w1, const float* __restrict__ b1,
    const float* __restrict__ w2, const float* __restrict__ b2,
    float* __restrict__ att)
{
  int b = blockIdx.x;
  int c = threadIdx.x;   // 128 threads
  __shared__ float p[C_CH];
  __shared__ float h[HIDDEN];

  float s = 0.f, m = -INFINITY;
  #pragma unroll
  for (int k = 0; k < NSTRIP; ++k) {
    s += psum[(b * C_CH + c) * NSTRIP + k];
    m = fmaxf(m, pmax[(b * C_CH + c) * NSTRIP + k]);
  }
  p[c] = s * (1.f / 16641.f) + m;
  __syncthreads();

  if (c < HIDDEN) {
    float acc = b1[c];
    for (int k = 0; k < C_CH; ++k) acc += p[k] * w1[k * HIDDEN + c];
    h[c] = fmaxf(acc, 0.f);
  }
  __syncthreads();

  float acc = b2[c];
  #pragma unroll
  for (int j = 0; j < HIDDEN; ++j) acc += h[j] * w2[j * C_CH + c];
  att[b * C_CH + c] = 1.f / (1.f + expf(-acc));
}

// -------- Kernel 4: 5x5 conv (2->1 ch, zero pad) + sigmoid ------------------
__global__ __launch_bounds__(256) void conv_kernel(
    const float* __restrict__ sa_in, const float* __restrict__ w_sa,
    float* __restrict__ sa)
{
  int b = blockIdx.y;
  int s = blockIdx.x * 256 + threadIdx.x;
  if (s >= SP) return;
  int i = s / WO;
  int j = s - i * WO;
  float acc = 0.f;
  const float* in0 = sa_in + (size_t)b * 2 * SP;
  #pragma unroll
  for (int ch = 0; ch < 2; ++ch) {
    const float* in = in0 + ch * SP;
    #pragma unroll
    for (int u = 0; u < 5; ++u) {
      int ii = i + u - 2;
      if (ii < 0 || ii >= HO) continue;
      #pragma unroll
      for (int v = 0; v < 5; ++v) {
        int jj = j + v - 2;
        if (jj < 0 || jj >= WO) continue;
        acc += in[ii * WO + jj] * w_sa[(ch * 5 + u) * 5 + v];
      }
    }
  }
  sa[(size_t)b * SP + s] = 1.f / (1.f + expf(-acc));
}

// -------- Kernel 4b: bilinear resize sa (8,129,129) -> sar (8,256,256) ------
__global__ __launch_bounds__(256) void resize_kernel(
    const float* __restrict__ sa, float* __restrict__ sar)
{
  int idx = blockIdx.x * 256 + threadIdx.x;   // 8*256*256 = 524288
  int J = idx & 255;
  int I = (idx >> 8) & 255;
  int b = idx >> 16;

  float ti = (I + 0.5f) * (129.f / 256.f) - 0.5f;
  ti = fminf(fmaxf(ti, 0.f), 128.f);
  int i0 = (int)ti;
  float fi = ti - (float)i0;
  int i1 = min(i0 + 1, 128);

  float tj = (J + 0.5f) * (129.f / 256.f) - 0.5f;
  tj = fminf(fmaxf(tj, 0.f), 128.f);
  int jj0 = (int)tj;
  float fj = tj - (float)jj0;
  int jj1 = min(jj0 + 1, 128);

  const float* r0 = sa + ((size_t)b * HO + i0) * WO;
  const float* r1 = sa + ((size_t)b * HO + i1) * WO;
  float v0 = r0[jj0] + fj * (r0[jj1] - r0[jj0]);
  float v1 = r1[jj0] + fj * (r1[jj1] - r1[jj0]);
  sar[idx] = v0 + fi * (v1 - v0);
}

// -------- Kernel 5: out = x * att[b,c] * sar (pure stream) ------------------
__global__ __launch_bounds__(256) void final2_kernel(
    const float* __restrict__ x, const float* __restrict__ att,
    const float* __restrict__ sar, float* __restrict__ out)
{
  // bid = ((b*64 + rg)*4 + cchunk); block: 4 rows x 256 cols x 32 channels
  int bid = blockIdx.x;
  int cchunk = bid & 3;
  int rg  = (bid >> 2) & 63;
  int b   = bid >> 8;
  int t = threadIdx.x;
  int r = t >> 6;          // 0..3
  int col4 = t & 63;
  int I = rg * 4 + r;

  __shared__ float att_s[32];
  if (t < 32) att_s[t] = att[b * C_CH + cchunk * 32 + t];
  __syncthreads();

  float4 sv = reinterpret_cast<const float4*>(sar + ((size_t)b * 256 + I) * 256)[col4];

  size_t base4 = ((size_t)(b * C_CH + cchunk * 32) * 256 + I) * 64 + col4;
  const float4* xp = reinterpret_cast<const float4*>(x);
  float4* op = reinterpret_cast<float4*>(out);
  #pragma unroll 4
  for (int cc = 0; cc < 32; ++cc) {
    float a = att_s[cc];
    float4 xv = xp[base4 + (size_t)cc * 16384];
    float4 ov;
    ov.x = xv.x * a * sv.x;
    ov.y = xv.y * a * sv.y;
    ov.z = xv.z * a * sv.z;
    ov.w = xv.w * a * sv.w;
    op[base4 + (size_t)cc * 16384] = ov;
  }
}

extern "C" void kernel_launch(void* const* d_in, const int* in_sizes, int n_in,
                              void* d_out, int out_size, void* d_ws, size_t ws_size,
                              hipStream_t stream) {
  const float* x    = (const float*)d_in[0];
  const float* w1   = (const float*)d_in[1];
  const float* b1   = (const float*)d_in[2];
  const float* w2   = (const float*)d_in[3];
  const float* b2   = (const float*)d_in[4];
  const float* w_sa = (const float*)d_in[5];
  float* out = (float*)d_out;

  // workspace layout (floats)
  float* chpsum = (float*)d_ws;                          // B*NGROUP*SP
  float* chpmax = chpsum + (size_t)B_N * NGROUP * SP;    // B*NGROUP*SP
  float* psum   = chpmax + (size_t)B_N * NGROUP * SP;    // B*C*NSTRIP
  float* pmax   = psum + B_N * C_CH * NSTRIP;            // B*C*NSTRIP
  float* sa_in  = pmax + B_N * C_CH * NSTRIP;            // B*2*SP
  float* att    = sa_in + (size_t)B_N * 2 * SP;          // B*C
  float* sa     = att + B_N * C_CH;                      // B*SP
  float* sar    = sa + (size_t)B_N * SP;                 // B*256*256

  hipLaunchKernelGGL(dwt_fused_kernel, dim3(B_N * NSTRIP * NGROUP), dim3(256), 0, stream,
                     x, psum, pmax, chpsum, chpmax);
  hipLaunchKernelGGL(combine_kernel, dim3((SP + 255) / 256, B_N), dim3(256), 0, stream,
                     chpsum, chpmax, sa_in);
  hipLaunchKernelGGL(mlp_kernel, dim3(B_N), dim3(C_CH), 0, stream,
                     psum, pmax, w1, b1, w2, b2, att);
  hipLaunchKernelGGL(conv_kernel, dim3((SP + 255) / 256, B_N), dim3(256), 0, stream,
                     sa_in, w_sa, sa);
  hipLaunchKernelGGL(resize_kernel, dim3(B_N * H_IN * W_IN / 256), dim3(256), 0, stream,
                     sa, sar);
  hipLaunchKernelGGL(final2_kernel, dim3(B_N * 64 * 4), dim3(256), 0, stream,
                     x, att, sar, out);
}

// Round 5
// 218.696 us; speedup vs baseline: 1.3925x; 1.3925x over previous
//
#include <hip/hip_runtime.h>
#include <math.h>

#define B_N 8
#define C_CH 128
#define H_IN 256
#define W_IN 256
#define HO 129
#define WO 129
#define SP (HO*WO)          // 16641
#define HIDDEN 11
#define NSTR 16             // vertical row-strips for dwt
#define SH 8                // output rows per strip (last strip: +1 special)
#define NGE 32              // cross-channel partial groups per batch
#define CPW 4               // channels per wave
#define WOP 132             // padded row stride for partials (even, 8B-aligned)

__constant__ float c_lo[4] = {-0.12940952255126037f, 0.2241438680420134f,
                               0.8365163037378079f,  0.48296291314453416f};
__constant__ float c_hi[4] = {-0.48296291314453416f, 0.8365163037378079f,
                              -0.2241438680420134f, -0.12940952255126037f};

// -------- Kernel 1: streaming DWT2, zero LDS, zero barriers -----------------
// Block = (b, gb, strip) of 4 waves; wave = 4 channels; lane = output cols
// {2l, 2l+1} (+ col 128 on lane 63). Vertical filter via 4-deep register
// window streamed over input rows. Emits per-channel strip stats and
// cross-channel (sum,max) partials; never materializes cA/cH.
__global__ __launch_bounds__(256, 4) void dwt_stream_kernel(
    const float* __restrict__ x,
    float* __restrict__ psum, float* __restrict__ pmax,
    float* __restrict__ chpsum, float* __restrict__ chpmax)
{
  const int bid  = blockIdx.x;            // ((b*8 + gb)*NSTR + s)
  const int s    = bid & (NSTR - 1);
  const int gb   = (bid >> 4) & 7;
  const int b    = bid >> 7;
  const int tid  = threadIdx.x;
  const int lane = tid & 63;
  const int wave = tid >> 6;
  const int g    = gb * 4 + wave;         // 0..31
  const int cb   = g * CPW;               // base channel
  const int j0   = s * SH;

  const float* xb = x + ((size_t)(b * C_CH + cb)) * (H_IN * W_IN) + 4 * lane;

  // rolling vertical windows: [ch][slot], slot 0 -> col 2l, 1 -> col 2l+1,
  // 2 -> col 128 (valid on lane 63 only)
  float W0[CPW][3], W1[CPW][3], W2[CPW][3], W3[CPW][3];
  #pragma unroll
  for (int ch = 0; ch < CPW; ++ch)
    #pragma unroll
    for (int sl = 0; sl < 3; ++sl) {
      W0[ch][sl] = 0.f; W1[ch][sl] = 0.f; W2[ch][sl] = 0.f; W3[ch][sl] = 0.f;
    }

  float sA[CPW], mH[CPW];
  #pragma unroll
  for (int ch = 0; ch < CPW; ++ch) { sA[ch] = 0.f; mH[ch] = -INFINITY; }

  const float l03 = c_lo[0] + c_lo[3], l12 = c_lo[1] + c_lo[2];
  const float h03 = c_hi[0] + c_hi[3], h12 = c_hi[1] + c_hi[2];

  float* cps = chpsum + ((size_t)(b * NGE + g)) * (HO * WOP);
  float* cpm = chpmax + ((size_t)(b * NGE + g)) * (HO * WOP);

  // ---- row step: horizontal lowpass + window shift ----
  auto row_step = [&](int r) {
    #pragma unroll
    for (int ch = 0; ch < CPW; ++ch) {
      float4 v = *reinterpret_cast<const float4*>(xb + ch * (H_IN * W_IN) + r * W_IN);
      float pz = __shfl_up(v.z, 1);
      float pw = __shfl_up(v.w, 1);
      // col 2l  (lane 0 = global col 0: left reflection folds to own regs)
      float l0 = (lane == 0)
                   ? (l03 * v.y + l12 * v.x)
                   : (c_lo[0]*v.y + c_lo[1]*v.x + c_lo[2]*pw + c_lo[3]*pz);
      // col 2l+1 (all taps in own float4)
      float l1 = c_lo[0]*v.w + c_lo[1]*v.z + c_lo[2]*v.y + c_lo[3]*v.x;
      // col 128 (lane63: right reflection folds to own regs: x254=v.z x255=v.w)
      float l2 = l03 * v.z + l12 * v.w;
      W0[ch][0]=W1[ch][0]; W1[ch][0]=W2[ch][0]; W2[ch][0]=W3[ch][0]; W3[ch][0]=l0;
      W0[ch][1]=W1[ch][1]; W1[ch][1]=W2[ch][1]; W2[ch][1]=W3[ch][1]; W3[ch][1]=l1;
      W0[ch][2]=W1[ch][2]; W1[ch][2]=W2[ch][2]; W2[ch][2]=W3[ch][2]; W3[ch][2]=l2;
    }
  };

  // ---- emit helpers ----
  auto store_cross = [&](int jo, float cs0, float cs1, float cs2,
                         float cm0, float cm1, float cm2) {
    float* ps = cps + (size_t)jo * WOP;
    float* pm = cpm + (size_t)jo * WOP;
    *reinterpret_cast<float2*>(ps + 2 * lane) = make_float2(cs0, cs1);
    *reinterpret_cast<float2*>(pm + 2 * lane) = make_float2(cm0, cm1);
    if (lane == 63) { ps[128] = cs2; pm[128] = cm2; }
  };

  auto emit_normal = [&](int jo) {
    float cs0=0.f, cs1=0.f, cs2=0.f, cm0=-INFINITY, cm1=-INFINITY, cm2=-INFINITY;
    #pragma unroll
    for (int ch = 0; ch < CPW; ++ch) {
      float a0 = c_lo[0]*W3[ch][0] + c_lo[1]*W2[ch][0] + c_lo[2]*W1[ch][0] + c_lo[3]*W0[ch][0];
      float h0 = c_hi[0]*W3[ch][0] + c_hi[1]*W2[ch][0] + c_hi[2]*W1[ch][0] + c_hi[3]*W0[ch][0];
      float a1 = c_lo[0]*W3[ch][1] + c_lo[1]*W2[ch][1] + c_lo[2]*W1[ch][1] + c_lo[3]*W0[ch][1];
      float h1 = c_hi[0]*W3[ch][1] + c_hi[1]*W2[ch][1] + c_hi[2]*W1[ch][1] + c_hi[3]*W0[ch][1];
      float a2 = c_lo[0]*W3[ch][2] + c_lo[1]*W2[ch][2] + c_lo[2]*W1[ch][2] + c_lo[3]*W0[ch][2];
      float h2 = c_hi[0]*W3[ch][2] + c_hi[1]*W2[ch][2] + c_hi[2]*W1[ch][2] + c_hi[3]*W0[ch][2];
      sA[ch] += a0 + a1;
      mH[ch] = fmaxf(mH[ch], fmaxf(h0, h1));
      if (lane == 63) { sA[ch] += a2; mH[ch] = fmaxf(mH[ch], h2); }
      cs0 += a0 + h0; cs1 += a1 + h1; cs2 += a2 + h2;
      cm0 = fmaxf(cm0, fmaxf(a0, h0));
      cm1 = fmaxf(cm1, fmaxf(a1, h1));
      cm2 = fmaxf(cm2, fmaxf(a2, h2));
    }
    store_cross(jo, cs0, cs1, cs2, cm0, cm1, cm2);
  };

  // top boundary (j=0): rows {1,0,0,1} -> (c0+c3)*low1 + (c1+c2)*low0,
  // window after rows 0,1: W2=low0, W3=low1
  auto emit_top = [&]() {
    float cs0=0.f, cs1=0.f, cs2=0.f, cm0=-INFINITY, cm1=-INFINITY, cm2=-INFINITY;
    #pragma unroll
    for (int ch = 0; ch < CPW; ++ch) {
      float a0 = l03*W3[ch][0] + l12*W2[ch][0];
      float h0 = h03*W3[ch][0] + h12*W2[ch][0];
      float a1 = l03*W3[ch][1] + l12*W2[ch][1];
      float h1 = h03*W3[ch][1] + h12*W2[ch][1];
      float a2 = l03*W3[ch][2] + l12*W2[ch][2];
      float h2 = h03*W3[ch][2] + h12*W2[ch][2];
      sA[ch] += a0 + a1;
      mH[ch] = fmaxf(mH[ch], fmaxf(h0, h1));
      if (lane == 63) { sA[ch] += a2; mH[ch] = fmaxf(mH[ch], h2); }
      cs0 += a0 + h0; cs1 += a1 + h1; cs2 += a2 + h2;
      cm0 = fmaxf(cm0, fmaxf(a0, h0));
      cm1 = fmaxf(cm1, fmaxf(a1, h1));
      cm2 = fmaxf(cm2, fmaxf(a2, h2));
    }
    store_cross(0, cs0, cs1, cs2, cm0, cm1, cm2);
  };

  // bottom boundary (j=128): rows {254,255,255,254} -> (c0+c3)*low254 +
  // (c1+c2)*low255; window after row 255: W2=low254, W3=low255
  auto emit_bot = [&]() {
    float cs0=0.f, cs1=0.f, cs2=0.f, cm0=-INFINITY, cm1=-INFINITY, cm2=-INFINITY;
    #pragma unroll
    for (int ch = 0; ch < CPW; ++ch) {
      float a0 = l03*W2[ch][0] + l12*W3[ch][0];
      float h0 = h03*W2[ch][0] + h12*W3[ch][0];
      float a1 = l03*W2[ch][1] + l12*W3[ch][1];
      float h1 = h03*W2[ch][1] + h12*W3[ch][1];
      float a2 = l03*W2[ch][2] + l12*W3[ch][2];
      float h2 = h03*W2[ch][2] + h12*W3[ch][2];
      sA[ch] += a0 + a1;
      mH[ch] = fmaxf(mH[ch], fmaxf(h0, h1));
      if (lane == 63) { sA[ch] += a2; mH[ch] = fmaxf(mH[ch], h2); }
      cs0 += a0 + h0; cs1 += a1 + h1; cs2 += a2 + h2;
      cm0 = fmaxf(cm0, fmaxf(a0, h0));
      cm1 = fmaxf(cm1, fmaxf(a1, h1));
      cm2 = fmaxf(cm2, fmaxf(a2, h2));
    }
    store_cross(128, cs0, cs1, cs2, cm0, cm1, cm2);
  };

  // ---- stream ----
  if (s == 0) {
    row_step(0); row_step(1);
    emit_top();
    for (int k = 1; k < SH; ++k) {
      row_step(2*k); row_step(2*k + 1);
      emit_normal(k);
    }
  } else {
    row_step(2*j0 - 2); row_step(2*j0 - 1);      // window warm-up (halo)
    for (int k = j0; k < j0 + SH; ++k) {
      row_step(2*k); row_step(2*k + 1);
      emit_normal(k);
    }
    if (s == NSTR - 1) emit_bot();
  }

  // ---- per-channel strip reduction (wave-local, deterministic) ----
  #pragma unroll
  for (int ch = 0; ch < CPW; ++ch) {
    float ssum = sA[ch], smax = mH[ch];
    for (int off = 32; off > 0; off >>= 1) {
      ssum += __shfl_down(ssum, off, 64);
      smax = fmaxf(smax, __shfl_down(smax, off, 64));
    }
    if (lane == 0) {
      size_t bc = (size_t)(b * C_CH + cb + ch);
      psum[bc * NSTR + s] = ssum;
      pmax[bc * NSTR + s] = smax;
    }
  }
}

// -------- Kernel 2: combine group partials -> sa_in -------------------------
__global__ __launch_bounds__(256) void combine_kernel(
    const float* __restrict__ chpsum, const float* __restrict__ chpmax,
    float* __restrict__ sa_in)
{
  int b = blockIdx.y;
  int s = blockIdx.x * 256 + threadIdx.x;
  if (s >= SP) return;
  int jo  = s / WO;
  int col = s - jo * WO;
  size_t off = (size_t)jo * WOP + col;
  float sum = 0.f, mx = -INFINITY;
  #pragma unroll 4
  for (int gg = 0; gg < NGE; ++gg) {
    sum += chpsum[((size_t)(b * NGE + gg)) * (HO * WOP) + off];
    mx = fmaxf(mx, chpmax[((size_t)(b * NGE + gg)) * (HO * WOP) + off]);
  }
  sa_in[(size_t)b * 2 * SP + s]      = sum * (1.f / 256.f);
  sa_in[(size_t)b * 2 * SP + SP + s] = mx;
}

// -------- Kernel 3: channel-attention MLP -----------------------------------
__global__ __launch_bounds__(128) void mlp_kernel(
    const float* __restrict__ psum, const float* __restrict__ pmax,
    const float* __restrict__ w1, const float* __restrict__ b1,
    const float* __restrict__ w2, const float* __restrict__ b2,
    float* __restrict__ att)
{
  int b = blockIdx.x;
  int c = threadIdx.x;   // 128 threads
  __shared__ float p[C_CH];
  __shared__ float h[HIDDEN];

  float s = 0.f, m = -INFINITY;
  #pragma unroll
  for (int k = 0; k < NSTR; ++k) {
    s += psum[(b * C_CH + c) * NSTR + k];
    m = fmaxf(m, pmax[(b * C_CH + c) * NSTR + k]);
  }
  p[c] = s * (1.f / 16641.f) + m;
  __syncthreads();

  if (c < HIDDEN) {
    float acc = b1[c];
    for (int k = 0; k < C_CH; ++k) acc += p[k] * w1[k * HIDDEN + c];
    h[c] = fmaxf(acc, 0.f);
  }
  __syncthreads();

  float acc = b2[c];
  #pragma unroll
  for (int j = 0; j < HIDDEN; ++j) acc += h[j] * w2[j * C_CH + c];
  att[b * C_CH + c] = 1.f / (1.f + expf(-acc));
}

// -------- Kernel 4: 5x5 conv (2->1 ch, zero pad) + sigmoid ------------------
__global__ __launch_bounds__(256) void conv_kernel(
    const float* __restrict__ sa_in, const float* __restrict__ w_sa,
    float* __restrict__ sa)
{
  int b = blockIdx.y;
  int s = blockIdx.x * 256 + threadIdx.x;
  if (s >= SP) return;
  int i = s / WO;
  int j = s - i * WO;
  float acc = 0.f;
  const float* in0 = sa_in + (size_t)b * 2 * SP;
  #pragma unroll
  for (int ch = 0; ch < 2; ++ch) {
    const float* in = in0 + ch * SP;
    #pragma unroll
    for (int u = 0; u < 5; ++u) {
      int ii = i + u - 2;
      if (ii < 0 || ii >= HO) continue;
      #pragma unroll
      for (int v = 0; v < 5; ++v) {
        int jj = j + v - 2;
        if (jj < 0 || jj >= WO) continue;
        acc += in[ii * WO + jj] * w_sa[(ch * 5 + u) * 5 + v];
      }
    }
  }
  sa[(size_t)b * SP + s] = 1.f / (1.f + expf(-acc));
}

// -------- Kernel 4b: bilinear resize sa (8,129,129) -> sar (8,256,256) ------
__global__ __launch_bounds__(256) void resize_kernel(
    const float* __restrict__ sa, float* __restrict__ sar)
{
  int idx = blockIdx.x * 256 + threadIdx.x;   // 8*256*256 = 524288
  int J = idx & 255;
  int I = (idx >> 8) & 255;
  int b = idx >> 16;

  float ti = (I + 0.5f) * (129.f / 256.f) - 0.5f;
  ti = fminf(fmaxf(ti, 0.f), 128.f);
  int i0 = (int)ti;
  float fi = ti - (float)i0;
  int i1 = min(i0 + 1, 128);

  float tj = (J + 0.5f) * (129.f / 256.f) - 0.5f;
  tj = fminf(fmaxf(tj, 0.f), 128.f);
  int jj0 = (int)tj;
  float fj = tj - (float)jj0;
  int jj1 = min(jj0 + 1, 128);

  const float* r0 = sa + ((size_t)b * HO + i0) * WO;
  const float* r1 = sa + ((size_t)b * HO + i1) * WO;
  float v0 = r0[jj0] + fj * (r0[jj1] - r0[jj0]);
  float v1 = r1[jj0] + fj * (r1[jj1] - r1[jj0]);
  sar[idx] = v0 + fi * (v1 - v0);
}

// -------- Kernel 5: out = x * att[b,c] * sar (pure stream) ------------------
__global__ __launch_bounds__(256) void final2_kernel(
    const float* __restrict__ x, const float* __restrict__ att,
    const float* __restrict__ sar, float* __restrict__ out)
{
  // bid = ((b*64 + rg)*4 + cchunk); block: 4 rows x 256 cols x 32 channels
  int bid = blockIdx.x;
  int cchunk = bid & 3;
  int rg  = (bid >> 2) & 63;
  int b   = bid >> 8;
  int t = threadIdx.x;
  int r = t >> 6;          // 0..3
  int col4 = t & 63;
  int I = rg * 4 + r;

  __shared__ float att_s[32];
  if (t < 32) att_s[t] = att[b * C_CH + cchunk * 32 + t];
  __syncthreads();

  float4 sv = reinterpret_cast<const float4*>(sar + ((size_t)b * 256 + I) * 256)[col4];

  size_t base4 = ((size_t)(b * C_CH + cchunk * 32) * 256 + I) * 64 + col4;
  const float4* xp = reinterpret_cast<const float4*>(x);
  float4* op = reinterpret_cast<float4*>(out);
  #pragma unroll 4
  for (int cc = 0; cc < 32; ++cc) {
    float a = att_s[cc];
    float4 xv = xp[base4 + (size_t)cc * 16384];
    float4 ov;
    ov.x = xv.x * a * sv.x;
    ov.y = xv.y * a * sv.y;
    ov.z = xv.z * a * sv.z;
    ov.w = xv.w * a * sv.w;
    op[base4 + (size_t)cc * 16384] = ov;
  }
}

extern "C" void kernel_launch(void* const* d_in, const int* in_sizes, int n_in,
                              void* d_out, int out_size, void* d_ws, size_t ws_size,
                              hipStream_t stream) {
  const float* x    = (const float*)d_in[0];
  const float* w1   = (const float*)d_in[1];
  const float* b1   = (const float*)d_in[2];
  const float* w2   = (const float*)d_in[3];
  const float* b2   = (const float*)d_in[4];
  const float* w_sa = (const float*)d_in[5];
  float* out = (float*)d_out;

  // workspace layout (floats)
  float* chpsum = (float*)d_ws;                            // B*NGE*HO*WOP
  float* chpmax = chpsum + (size_t)B_N * NGE * HO * WOP;   // B*NGE*HO*WOP
  float* psum   = chpmax + (size_t)B_N * NGE * HO * WOP;   // B*C*NSTR
  float* pmax   = psum + B_N * C_CH * NSTR;                // B*C*NSTR
  float* sa_in  = pmax + B_N * C_CH * NSTR;                // B*2*SP
  float* att    = sa_in + (size_t)B_N * 2 * SP;            // B*C
  float* sa     = att + B_N * C_CH;                        // B*SP
  float* sar    = sa + (size_t)B_N * SP;                   // B*256*256

  hipLaunchKernelGGL(dwt_stream_kernel, dim3(B_N * 8 * NSTR), dim3(256), 0, stream,
                     x, psum, pmax, chpsum, chpmax);
  hipLaunchKernelGGL(combine_kernel, dim3((SP + 255) / 256, B_N), dim3(256), 0, stream,
                     chpsum, chpmax, sa_in);
  hipLaunchKernelGGL(mlp_kernel, dim3(B_N), dim3(C_CH), 0, stream,
                     psum, pmax, w1, b1, w2, b2, att);
  hipLaunchKernelGGL(conv_kernel, dim3((SP + 255) / 256, B_N), dim3(256), 0, stream,
                     sa_in, w_sa, sa);
  hipLaunchKernelGGL(resize_kernel, dim3(B_N * H_IN * W_IN / 256), dim3(256), 0, stream,
                     sa, sar);
  hipLaunchKernelGGL(final2_kernel, dim3(B_N * 64 * 4), dim3(256), 0, stream,
                     x, att, sar, out);
}

// Round 7
// 210.581 us; speedup vs baseline: 1.4462x; 1.0385x over previous
//
#include <hip/hip_runtime.h>
#include <math.h>

#define B_N 8
#define C_CH 128
#define H_IN 256
#define W_IN 256
#define HO 129
#define WO 129
#define SP (HO*WO)          // 16641
#define HIDDEN 11
#define NSTR 16             // vertical row-strips for dwt
#define SH 8                // output rows per strip
#define NGE 32              // cross-channel partial groups per batch
#define CPW 4               // channels per wave
#define WOP 132             // padded row stride for partials (even, 8B-aligned)

__constant__ float c_lo[4] = {-0.12940952255126037f, 0.2241438680420134f,
                               0.8365163037378079f,  0.48296291314453416f};
__constant__ float c_hi[4] = {-0.48296291314453416f, 0.8365163037378079f,
                              -0.2241438680420134f, -0.12940952255126037f};

// -------- Kernel 1: streaming DWT2, zero LDS, zero barriers -----------------
// Block = (b, gb, strip) of 4 waves; wave = 4 channels; lane = output cols
// {2l, 2l+1} (+ col 128 on lane 63). Vertical filter via 4-deep register
// window; explicit double-buffered row-pair loads (cur/nxt) so the next
// pair's 8 loads are in flight under the current pair's VALU work.
// No launch_bounds min-occupancy: let the allocator keep the pipeline in regs.
__global__ __launch_bounds__(256) void dwt_stream_kernel(
    const float* __restrict__ x,
    float* __restrict__ psum, float* __restrict__ pmax,
    float* __restrict__ chpsum, float* __restrict__ chpmax)
{
  const int bid  = blockIdx.x;            // ((b*8 + gb)*NSTR + s)
  const int s    = bid & (NSTR - 1);
  const int gb   = (bid >> 4) & 7;
  const int b    = bid >> 7;
  const int tid  = threadIdx.x;
  const int lane = tid & 63;
  const int wave = tid >> 6;
  const int g    = gb * 4 + wave;         // 0..31
  const int cb   = g * CPW;               // base channel
  const int j0   = s * SH;

  const float* xb = x + ((size_t)(b * C_CH + cb)) * (H_IN * W_IN) + 4 * lane;

  // rolling vertical windows: [ch][slot], slot 0 -> col 2l, 1 -> col 2l+1,
  // 2 -> col 128 (valid on lane 63 only)
  float W0[CPW][3], W1[CPW][3], W2[CPW][3], W3[CPW][3];
  #pragma unroll
  for (int ch = 0; ch < CPW; ++ch)
    #pragma unroll
    for (int sl = 0; sl < 3; ++sl) {
      W0[ch][sl] = 0.f; W1[ch][sl] = 0.f; W2[ch][sl] = 0.f; W3[ch][sl] = 0.f;
    }

  float sA[CPW], mH[CPW];
  #pragma unroll
  for (int ch = 0; ch < CPW; ++ch) { sA[ch] = 0.f; mH[ch] = -INFINITY; }

  const float l03 = c_lo[0] + c_lo[3], l12 = c_lo[1] + c_lo[2];
  const float h03 = c_hi[0] + c_hi[3], h12 = c_hi[1] + c_hi[2];

  float* cps = chpsum + ((size_t)(b * NGE + g)) * (HO * WOP);
  float* cpm = chpmax + ((size_t)(b * NGE + g)) * (HO * WOP);

  // ---- double-buffered row-pair loads ----
  float4 cur0[CPW], cur1[CPW], nxt0[CPW], nxt1[CPW];

  auto load_pair = [&](int r, float4* v0, float4* v1) {
    #pragma unroll
    for (int ch = 0; ch < CPW; ++ch) {
      const float* p = xb + ch * (H_IN * W_IN) + r * W_IN;
      v0[ch] = *reinterpret_cast<const float4*>(p);
      v1[ch] = *reinterpret_cast<const float4*>(p + W_IN);
    }
  };

  // horizontal lowpass of one loaded row + window shift
  auto hrow = [&](float4 v, int ch) {
    float pz = __shfl_up(v.z, 1);
    float pw = __shfl_up(v.w, 1);
    // col 2l  (lane 0 = global col 0: left reflection folds to own regs)
    float l0 = (lane == 0)
                 ? (l03 * v.y + l12 * v.x)
                 : (c_lo[0]*v.y + c_lo[1]*v.x + c_lo[2]*pw + c_lo[3]*pz);
    // col 2l+1 (all taps in own float4)
    float l1 = c_lo[0]*v.w + c_lo[1]*v.z + c_lo[2]*v.y + c_lo[3]*v.x;
    // col 128 (lane63: right reflection folds to own regs: x254=v.z x255=v.w)
    float l2 = l03 * v.z + l12 * v.w;
    W0[ch][0]=W1[ch][0]; W1[ch][0]=W2[ch][0]; W2[ch][0]=W3[ch][0]; W3[ch][0]=l0;
    W0[ch][1]=W1[ch][1]; W1[ch][1]=W2[ch][1]; W2[ch][1]=W3[ch][1]; W3[ch][1]=l1;
    W0[ch][2]=W1[ch][2]; W1[ch][2]=W2[ch][2]; W2[ch][2]=W3[ch][2]; W3[ch][2]=l2;
  };

  // ---- emit helpers ----
  auto store_cross = [&](int jo, float cs0, float cs1, float cs2,
                         float cm0, float cm1, float cm2) {
    float* ps = cps + (size_t)jo * WOP;
    float* pm = cpm + (size_t)jo * WOP;
    *reinterpret_cast<float2*>(ps + 2 * lane) = make_float2(cs0, cs1);
    *reinterpret_cast<float2*>(pm + 2 * lane) = make_float2(cm0, cm1);
    if (lane == 63) { ps[128] = cs2; pm[128] = cm2; }
  };

  auto emit_normal = [&](int jo) {
    float cs0=0.f, cs1=0.f, cs2=0.f, cm0=-INFINITY, cm1=-INFINITY, cm2=-INFINITY;
    #pragma unroll
    for (int ch = 0; ch < CPW; ++ch) {
      float a0 = c_lo[0]*W3[ch][0] + c_lo[1]*W2[ch][0] + c_lo[2]*W1[ch][0] + c_lo[3]*W0[ch][0];
      float h0 = c_hi[0]*W3[ch][0] + c_hi[1]*W2[ch][0] + c_hi[2]*W1[ch][0] + c_hi[3]*W0[ch][0];
      float a1 = c_lo[0]*W3[ch][1] + c_lo[1]*W2[ch][1] + c_lo[2]*W1[ch][1] + c_lo[3]*W0[ch][1];
      float h1 = c_hi[0]*W3[ch][1] + c_hi[1]*W2[ch][1] + c_hi[2]*W1[ch][1] + c_hi[3]*W0[ch][1];
      float a2 = c_lo[0]*W3[ch][2] + c_lo[1]*W2[ch][2] + c_lo[2]*W1[ch][2] + c_lo[3]*W0[ch][2];
      float h2 = c_hi[0]*W3[ch][2] + c_hi[1]*W2[ch][2] + c_hi[2]*W1[ch][2] + c_hi[3]*W0[ch][2];
      sA[ch] += a0 + a1;
      mH[ch] = fmaxf(mH[ch], fmaxf(h0, h1));
      if (lane == 63) { sA[ch] += a2; mH[ch] = fmaxf(mH[ch], h2); }
      cs0 += a0 + h0; cs1 += a1 + h1; cs2 += a2 + h2;
      cm0 = fmaxf(cm0, fmaxf(a0, h0));
      cm1 = fmaxf(cm1, fmaxf(a1, h1));
      cm2 = fmaxf(cm2, fmaxf(a2, h2));
    }
    store_cross(jo, cs0, cs1, cs2, cm0, cm1, cm2);
  };

  // top boundary (j=0): rows {1,0,0,1}; window after rows 0,1: W2=low0, W3=low1
  auto emit_top = [&]() {
    float cs0=0.f, cs1=0.f, cs2=0.f, cm0=-INFINITY, cm1=-INFINITY, cm2=-INFINITY;
    #pragma unroll
    for (int ch = 0; ch < CPW; ++ch) {
      float a0 = l03*W3[ch][0] + l12*W2[ch][0];
      float h0 = h03*W3[ch][0] + h12*W2[ch][0];
      float a1 = l03*W3[ch][1] + l12*W2[ch][1];
      float h1 = h03*W3[ch][1] + h12*W2[ch][1];
      float a2 = l03*W3[ch][2] + l12*W2[ch][2];
      float h2 = h03*W3[ch][2] + h12*W2[ch][2];
      sA[ch] += a0 + a1;
      mH[ch] = fmaxf(mH[ch], fmaxf(h0, h1));
      if (lane == 63) { sA[ch] += a2; mH[ch] = fmaxf(mH[ch], h2); }
      cs0 += a0 + h0; cs1 += a1 + h1; cs2 += a2 + h2;
      cm0 = fmaxf(cm0, fmaxf(a0, h0));
      cm1 = fmaxf(cm1, fmaxf(a1, h1));
      cm2 = fmaxf(cm2, fmaxf(a2, h2));
    }
    store_cross(0, cs0, cs1, cs2, cm0, cm1, cm2);
  };

  // bottom boundary (j=128): rows {254,255,255,254}; after row 255:
  // W2=low254, W3=low255
  auto emit_bot = [&]() {
    float cs0=0.f, cs1=0.f, cs2=0.f, cm0=-INFINITY, cm1=-INFINITY, cm2=-INFINITY;
    #pragma unroll
    for (int ch = 0; ch < CPW; ++ch) {
      float a0 = l03*W2[ch][0] + l12*W3[ch][0];
      float h0 = h03*W2[ch][0] + h12*W3[ch][0];
      float a1 = l03*W2[ch][1] + l12*W3[ch][1];
      float h1 = h03*W2[ch][1] + h12*W3[ch][1];
      float a2 = l03*W2[ch][2] + l12*W3[ch][2];
      float h2 = h03*W2[ch][2] + h12*W3[ch][2];
      sA[ch] += a0 + a1;
      mH[ch] = fmaxf(mH[ch], fmaxf(h0, h1));
      if (lane == 63) { sA[ch] += a2; mH[ch] = fmaxf(mH[ch], h2); }
      cs0 += a0 + h0; cs1 += a1 + h1; cs2 += a2 + h2;
      cm0 = fmaxf(cm0, fmaxf(a0, h0));
      cm1 = fmaxf(cm1, fmaxf(a1, h1));
      cm2 = fmaxf(cm2, fmaxf(a2, h2));
    }
    store_cross(128, cs0, cs1, cs2, cm0, cm1, cm2);
  };

  // ---- software-pipelined stream ----
  const int rstart = (s == 0) ? 0 : (2 * j0 - 2);
  const int npairs = (s == 0) ? SH : (SH + 1);   // s>0: pair 0 is halo warm-up

  load_pair(rstart, cur0, cur1);
  for (int p = 0; p < npairs; ++p) {
    const bool last = (p + 1 == npairs);
    if (!last) load_pair(rstart + 2 * (p + 1), nxt0, nxt1);

    #pragma unroll
    for (int ch = 0; ch < CPW; ++ch) { hrow(cur0[ch], ch); hrow(cur1[ch], ch); }

    if (s == 0) {
      if (p == 0) emit_top(); else emit_normal(p);
    } else if (p > 0) {
      emit_normal(j0 + p - 1);
    }

    if (!last) {
      #pragma unroll
      for (int ch = 0; ch < CPW; ++ch) { cur0[ch] = nxt0[ch]; cur1[ch] = nxt1[ch]; }
    }
  }
  if (s == NSTR - 1) emit_bot();

  // ---- per-channel strip reduction (wave-local, deterministic) ----
  #pragma unroll
  for (int ch = 0; ch < CPW; ++ch) {
    float ssum = sA[ch], smax = mH[ch];
    for (int off = 32; off > 0; off >>= 1) {
      ssum += __shfl_down(ssum, off, 64);
      smax = fmaxf(smax, __shfl_down(smax, off, 64));
    }
    if (lane == 0) {
      size_t bc = (size_t)(b * C_CH + cb + ch);
      psum[bc * NSTR + s] = ssum;
      pmax[bc * NSTR + s] = smax;
    }
  }
}

// -------- Kernel 2: combine group partials -> sa_in -------------------------
__global__ __launch_bounds__(256) void combine_kernel(
    const float* __restrict__ chpsum, const float* __restrict__ chpmax,
    float* __restrict__ sa_in)
{
  int b = blockIdx.y;
  int s = blockIdx.x * 256 + threadIdx.x;
  if (s >= SP) return;
  int jo  = s / WO;
  int col = s - jo * WO;
  size_t off = (size_t)jo * WOP + col;
  float sum = 0.f, mx = -INFINITY;
  #pragma unroll 4
  for (int gg = 0; gg < NGE; ++gg) {
    sum += chpsum[((size_t)(b * NGE + gg)) * (HO * WOP) + off];
    mx = fmaxf(mx, chpmax[((size_t)(b * NGE + gg)) * (HO * WOP) + off]);
  }
  sa_in[(size_t)b * 2 * SP + s]      = sum * (1.f / 256.f);
  sa_in[(size_t)b * 2 * SP + SP + s] = mx;
}

// -------- Kernel 3: channel-attention MLP -----------------------------------
__global__ __launch_bounds__(128) void mlp_kernel(
    const float* __restrict__ psum, const float* __restrict__ pmax,
    const float* __restrict__ w1, const float* __restrict__ b1,
    const float* __restrict__ w2, const float* __restrict__ b2,
    float* __restrict__ att)
{
  int b = blockIdx.x;
  int c = threadIdx.x;   // 128 threads
  __shared__ float p[C_CH];
  __shared__ float h[HIDDEN];

  float s = 0.f, m = -INFINITY;
  #pragma unroll
  for (int k = 0; k < NSTR; ++k) {
    s += psum[(b * C_CH + c) * NSTR + k];
    m = fmaxf(m, pmax[(b * C_CH + c) * NSTR + k]);
  }
  p[c] = s * (1.f / 16641.f) + m;
  __syncthreads();

  if (c < HIDDEN) {
    float acc = b1[c];
    for (int k = 0; k < C_CH; ++k) acc += p[k] * w1[k * HIDDEN + c];
    h[c] = fmaxf(acc, 0.f);
  }
  __syncthreads();

  float acc = b2[c];
  #pragma unroll
  for (int j = 0; j < HIDDEN; ++j) acc += h[j] * w2[j * C_CH + c];
  att[b * C_CH + c] = 1.f / (1.f + expf(-acc));
}

// -------- Kernel 4: 5x5 conv (2->1 ch, zero pad) + sigmoid ------------------
__global__ __launch_bounds__(256) void conv_kernel(
    const float* __restrict__ sa_in, const float* __restrict__ w_sa,
    float* __restrict__ sa)
{
  int b = blockIdx.y;
  int s = blockIdx.x * 256 + threadIdx.x;
  if (s >= SP) return;
  int i = s / WO;
  int j = s - i * WO;
  float acc = 0.f;
  const float* in0 = sa_in + (size_t)b * 2 * SP;
  #pragma unroll
  for (int ch = 0; ch < 2; ++ch) {
    const float* in = in0 + ch * SP;
    #pragma unroll
    for (int u = 0; u < 5; ++u) {
      int ii = i + u - 2;
      if (ii < 0 || ii >= HO) continue;
      #pragma unroll
      for (int v = 0; v < 5; ++v) {
        int jj = j + v - 2;
        if (jj < 0 || jj >= WO) continue;
        acc += in[ii * WO + jj] * w_sa[(ch * 5 + u) * 5 + v];
      }
    }
  }
  sa[(size_t)b * SP + s] = 1.f / (1.f + expf(-acc));
}

// -------- Kernel 4b: bilinear resize sa (8,129,129) -> sar (8,256,256) ------
__global__ __launch_bounds__(256) void resize_kernel(
    const float* __restrict__ sa, float* __restrict__ sar)
{
  int idx = blockIdx.x * 256 + threadIdx.x;   // 8*256*256 = 524288
  int J = idx & 255;
  int I = (idx >> 8) & 255;
  int b = idx >> 16;

  float ti = (I + 0.5f) * (129.f / 256.f) - 0.5f;
  ti = fminf(fmaxf(ti, 0.f), 128.f);
  int i0 = (int)ti;
  float fi = ti - (float)i0;
  int i1 = min(i0 + 1, 128);

  float tj = (J + 0.5f) * (129.f / 256.f) - 0.5f;
  tj = fminf(fmaxf(tj, 0.f), 128.f);
  int jj0 = (int)tj;
  float fj = tj - (float)jj0;
  int jj1 = min(jj0 + 1, 128);

  const float* r0 = sa + ((size_t)b * HO + i0) * WO;
  const float* r1 = sa + ((size_t)b * HO + i1) * WO;
  float v0 = r0[jj0] + fj * (r0[jj1] - r0[jj0]);
  float v1 = r1[jj0] + fj * (r1[jj1] - r1[jj0]);
  sar[idx] = v0 + fi * (v1 - v0);
}

// -------- Kernel 5: out = x * att[b,c] * sar (pure stream) ------------------
__global__ __launch_bounds__(256) void final2_kernel(
    const float* __restrict__ x, const float* __restrict__ att,
    const float* __restrict__ sar, float* __restrict__ out)
{
  // bid = ((b*64 + rg)*4 + cchunk); block: 4 rows x 256 cols x 32 channels
  int bid = blockIdx.x;
  int cchunk = bid & 3;
  int rg  = (bid >> 2) & 63;
  int b   = bid >> 8;
  int t = threadIdx.x;
  int r = t >> 6;          // 0..3
  int col4 = t & 63;
  int I = rg * 4 + r;

  __shared__ float att_s[32];
  if (t < 32) att_s[t] = att[b * C_CH + cchunk * 32 + t];
  __syncthreads();

  float4 sv = reinterpret_cast<const float4*>(sar + ((size_t)b * 256 + I) * 256)[col4];

  size_t base4 = ((size_t)(b * C_CH + cchunk * 32) * 256 + I) * 64 + col4;
  const float4* xp = reinterpret_cast<const float4*>(x);
  float4* op = reinterpret_cast<float4*>(out);
  #pragma unroll 4
  for (int cc = 0; cc < 32; ++cc) {
    float a = att_s[cc];
    float4 xv = xp[base4 + (size_t)cc * 16384];
    float4 ov;
    ov.x = xv.x * a * sv.x;
    ov.y = xv.y * a * sv.y;
    ov.z = xv.z * a * sv.z;
    ov.w = xv.w * a * sv.w;
    op[base4 + (size_t)cc * 16384] = ov;
  }
}

extern "C" void kernel_launch(void* const* d_in, const int* in_sizes, int n_in,
                              void* d_out, int out_size, void* d_ws, size_t ws_size,
                              hipStream_t stream) {
  const float* x    = (const float*)d_in[0];
  const float* w1   = (const float*)d_in[1];
  const float* b1   = (const float*)d_in[2];
  const float* w2   = (const float*)d_in[3];
  const float* b2   = (const float*)d_in[4];
  const float* w_sa = (const float*)d_in[5];
  float* out = (float*)d_out;

  // workspace layout (floats)
  float* chpsum = (float*)d_ws;                            // B*NGE*HO*WOP
  float* chpmax = chpsum + (size_t)B_N * NGE * HO * WOP;   // B*NGE*HO*WOP
  float* psum   = chpmax + (size_t)B_N * NGE * HO * WOP;   // B*C*NSTR
  float* pmax   = psum + B_N * C_CH * NSTR;                // B*C*NSTR
  float* sa_in  = pmax + B_N * C_CH * NSTR;                // B*2*SP
  float* att    = sa_in + (size_t)B_N * 2 * SP;            // B*C
  float* sa     = att + B_N * C_CH;                        // B*SP
  float* sar    = sa + (size_t)B_N * SP;                   // B*256*256

  hipLaunchKernelGGL(dwt_stream_kernel, dim3(B_N * 8 * NSTR), dim3(256), 0, stream,
                     x, psum, pmax, chpsum, chpmax);
  hipLaunchKernelGGL(combine_kernel, dim3((SP + 255) / 256, B_N), dim3(256), 0, stream,
                     chpsum, chpmax, sa_in);
  hipLaunchKernelGGL(mlp_kernel, dim3(B_N), dim3(C_CH), 0, stream,
                     psum, pmax, w1, b1, w2, b2, att);
  hipLaunchKernelGGL(conv_kernel, dim3((SP + 255) / 256, B_N), dim3(256), 0, stream,
                     sa_in, w_sa, sa);
  hipLaunchKernelGGL(resize_kernel, dim3(B_N * H_IN * W_IN / 256), dim3(256), 0, stream,
                     sa, sar);
  hipLaunchKernelGGL(final2_kernel, dim3(B_N * 64 * 4), dim3(256), 0, stream,
                     x, att, sar, out);
}

// Round 8
// 207.792 us; speedup vs baseline: 1.4656x; 1.0134x over previous
//
#include <hip/hip_runtime.h>
#include <math.h>

#define B_N 8
#define C_CH 128
#define H_IN 256
#define W_IN 256
#define HO 129
#define WO 129
#define SP (HO*WO)          // 16641
#define HIDDEN 11
#define NSTR 16             // vertical row-strips for dwt
#define SH 8                // output rows per strip
#define NGE 32              // cross-channel partial groups per batch
#define CPW 4               // channels per wave
#define WOP 132             // padded row stride for partials (even, 8B-aligned)

__constant__ float c_lo[4] = {-0.12940952255126037f, 0.2241438680420134f,
                               0.8365163037378079f,  0.48296291314453416f};
__constant__ float c_hi[4] = {-0.48296291314453416f, 0.8365163037378079f,
                              -0.2241438680420134f, -0.12940952255126037f};

// Per-channel streaming state: scalar/float4 members only (SROA-safe; no
// local arrays, no pointer-parameter lambdas -> nothing can go to scratch).
struct CS {
  float4 cur0, cur1, nxt0, nxt1;
  // w{depth}{slot}: rolling 4-deep vertical window; slot0=col 2l,
  // slot1=col 2l+1, slot2=col 128 (lane 63 only)
  float w00, w01, w02;
  float w10, w11, w12;
  float w20, w21, w22;
  float w30, w31, w32;
  float sA, mH;
};

// -------- Kernel 1: streaming DWT2, zero LDS, zero barriers -----------------
__global__ __launch_bounds__(256) void dwt_stream_kernel(
    const float* __restrict__ x,
    float* __restrict__ psum, float* __restrict__ pmax,
    float* __restrict__ chpsum, float* __restrict__ chpmax)
{
  const int bid  = blockIdx.x;            // ((b*8 + gb)*NSTR + s)
  const int s    = bid & (NSTR - 1);
  const int gb   = (bid >> 4) & 7;
  const int b    = bid >> 7;
  const int tid  = threadIdx.x;
  const int lane = tid & 63;
  const int wave = tid >> 6;
  const int g    = gb * 4 + wave;         // 0..31
  const int cb   = g * CPW;               // base channel
  const int j0   = s * SH;

  const float lo0 = c_lo[0], lo1 = c_lo[1], lo2 = c_lo[2], lo3 = c_lo[3];
  const float hi0 = c_hi[0], hi1 = c_hi[1], hi2 = c_hi[2], hi3 = c_hi[3];
  const float l03 = lo0 + lo3, l12 = lo1 + lo2;
  const float h03 = hi0 + hi3, h12 = hi1 + hi2;

  const float* xb0 = x + ((size_t)(b * C_CH + cb) + 0) * (H_IN * W_IN) + 4 * lane;
  const float* xb1 = xb0 + (H_IN * W_IN);
  const float* xb2 = xb1 + (H_IN * W_IN);
  const float* xb3 = xb2 + (H_IN * W_IN);

  CS s0, s1, s2, s3;
#define INIT(S) do { \
    S.w00=0.f;S.w01=0.f;S.w02=0.f; S.w10=0.f;S.w11=0.f;S.w12=0.f; \
    S.w20=0.f;S.w21=0.f;S.w22=0.f; S.w30=0.f;S.w31=0.f;S.w32=0.f; \
    S.sA=0.f; S.mH=-INFINITY; } while(0)
  INIT(s0); INIT(s1); INIT(s2); INIT(s3);

  float* cps = chpsum + ((size_t)(b * NGE + g)) * (HO * WOP);
  float* cpm = chpmax + ((size_t)(b * NGE + g)) * (HO * WOP);

#define LOADC(S, XB, R) do { \
    const float* _p = (XB) + (R) * W_IN; \
    S.cur0 = *reinterpret_cast<const float4*>(_p); \
    S.cur1 = *reinterpret_cast<const float4*>(_p + W_IN); } while(0)

#define LOADN(S, XB, R) do { \
    const float* _p = (XB) + (R) * W_IN; \
    S.nxt0 = *reinterpret_cast<const float4*>(_p); \
    S.nxt1 = *reinterpret_cast<const float4*>(_p + W_IN); } while(0)

#define SWAPB(S) do { S.cur0 = S.nxt0; S.cur1 = S.nxt1; } while(0)

  // horizontal lowpass of one row (float4 v) + 4-deep window shift
#define HROW(S, V) do { \
    float _pz = __shfl_up((V).z, 1); \
    float _pw = __shfl_up((V).w, 1); \
    float _l0 = (lane == 0) ? (l03 * (V).y + l12 * (V).x) \
                            : (lo0*(V).y + lo1*(V).x + lo2*_pw + lo3*_pz); \
    float _l1 = lo0*(V).w + lo1*(V).z + lo2*(V).y + lo3*(V).x; \
    float _l2 = l03 * (V).z + l12 * (V).w; \
    S.w00=S.w10; S.w10=S.w20; S.w20=S.w30; S.w30=_l0; \
    S.w01=S.w11; S.w11=S.w21; S.w21=S.w31; S.w31=_l1; \
    S.w02=S.w12; S.w12=S.w22; S.w22=S.w32; S.w32=_l2; } while(0)

  // vertical emit bodies; accumulate cross-channel cs/cm scalars
#define EMITN(S) do { \
    float _a0 = lo0*S.w30 + lo1*S.w20 + lo2*S.w10 + lo3*S.w00; \
    float _h0 = hi0*S.w30 + hi1*S.w20 + hi2*S.w10 + hi3*S.w00; \
    float _a1 = lo0*S.w31 + lo1*S.w21 + lo2*S.w11 + lo3*S.w01; \
    float _h1 = hi0*S.w31 + hi1*S.w21 + hi2*S.w11 + hi3*S.w01; \
    float _a2 = lo0*S.w32 + lo1*S.w22 + lo2*S.w12 + lo3*S.w02; \
    float _h2 = hi0*S.w32 + hi1*S.w22 + hi2*S.w12 + hi3*S.w02; \
    S.sA += _a0 + _a1; S.mH = fmaxf(S.mH, fmaxf(_h0, _h1)); \
    if (lane == 63) { S.sA += _a2; S.mH = fmaxf(S.mH, _h2); } \
    cs0 += _a0 + _h0; cs1 += _a1 + _h1; cs2 += _a2 + _h2; \
    cm0 = fmaxf(cm0, fmaxf(_a0, _h0)); \
    cm1 = fmaxf(cm1, fmaxf(_a1, _h1)); \
    cm2 = fmaxf(cm2, fmaxf(_a2, _h2)); } while(0)

  // top boundary (j=0): rows {1,0,0,1} -> (c0+c3)*low1 + (c1+c2)*low0
  // (after rows 0,1: w2*=low0, w3*=low1)
#define EMITT(S) do { \
    float _a0 = l03*S.w30 + l12*S.w20; float _h0 = h03*S.w30 + h12*S.w20; \
    float _a1 = l03*S.w31 + l12*S.w21; float _h1 = h03*S.w31 + h12*S.w21; \
    float _a2 = l03*S.w32 + l12*S.w22; float _h2 = h03*S.w32 + h12*S.w22; \
    S.sA += _a0 + _a1; S.mH = fmaxf(S.mH, fmaxf(_h0, _h1)); \
    if (lane == 63) { S.sA += _a2; S.mH = fmaxf(S.mH, _h2); } \
    cs0 += _a0 + _h0; cs1 += _a1 + _h1; cs2 += _a2 + _h2; \
    cm0 = fmaxf(cm0, fmaxf(_a0, _h0)); \
    cm1 = fmaxf(cm1, fmaxf(_a1, _h1)); \
    cm2 = fmaxf(cm2, fmaxf(_a2, _h2)); } while(0)

  // bottom boundary (j=128): rows {254,255,255,254} -> (c0+c3)*low254 +
  // (c1+c2)*low255 (after row 255: w2*=low254, w3*=low255)
#define EMITB(S) do { \
    float _a0 = l03*S.w20 + l12*S.w30; float _h0 = h03*S.w20 + h12*S.w30; \
    float _a1 = l03*S.w21 + l12*S.w31; float _h1 = h03*S.w21 + h12*S.w31; \
    float _a2 = l03*S.w22 + l12*S.w32; float _h2 = h03*S.w22 + h12*S.w32; \
    S.sA += _a0 + _a1; S.mH = fmaxf(S.mH, fmaxf(_h0, _h1)); \
    if (lane == 63) { S.sA += _a2; S.mH = fmaxf(S.mH, _h2); } \
    cs0 += _a0 + _h0; cs1 += _a1 + _h1; cs2 += _a2 + _h2; \
    cm0 = fmaxf(cm0, fmaxf(_a0, _h0)); \
    cm1 = fmaxf(cm1, fmaxf(_a1, _h1)); \
    cm2 = fmaxf(cm2, fmaxf(_a2, _h2)); } while(0)

#define STORE_CROSS(JO) do { \
    float* _ps = cps + (size_t)(JO) * WOP; \
    float* _pm = cpm + (size_t)(JO) * WOP; \
    *reinterpret_cast<float2*>(_ps + 2 * lane) = make_float2(cs0, cs1); \
    *reinterpret_cast<float2*>(_pm + 2 * lane) = make_float2(cm0, cm1); \
    if (lane == 63) { _ps[128] = cs2; _pm[128] = cm2; } } while(0)

  // ---- software-pipelined stream ----
  const int rstart = (s == 0) ? 0 : (2 * j0 - 2);
  const int npairs = (s == 0) ? SH : (SH + 1);   // s>0: pair 0 = halo warm-up

  LOADC(s0, xb0, rstart); LOADC(s1, xb1, rstart);
  LOADC(s2, xb2, rstart); LOADC(s3, xb3, rstart);

  for (int p = 0; p < npairs; ++p) {
    const bool last = (p + 1 == npairs);
    if (!last) {
      const int rn = rstart + 2 * (p + 1);
      LOADN(s0, xb0, rn); LOADN(s1, xb1, rn);
      LOADN(s2, xb2, rn); LOADN(s3, xb3, rn);
    }

    HROW(s0, s0.cur0); HROW(s0, s0.cur1);
    HROW(s1, s1.cur0); HROW(s1, s1.cur1);
    HROW(s2, s2.cur0); HROW(s2, s2.cur1);
    HROW(s3, s3.cur0); HROW(s3, s3.cur1);

    if (s == 0 || p > 0) {
      float cs0 = 0.f, cs1 = 0.f, cs2 = 0.f;
      float cm0 = -INFINITY, cm1 = -INFINITY, cm2 = -INFINITY;
      int jo;
      if (s == 0 && p == 0) {
        EMITT(s0); EMITT(s1); EMITT(s2); EMITT(s3);
        jo = 0;
      } else {
        EMITN(s0); EMITN(s1); EMITN(s2); EMITN(s3);
        jo = (s == 0) ? p : (j0 + p - 1);
      }
      STORE_CROSS(jo);
    }

    if (!last) { SWAPB(s0); SWAPB(s1); SWAPB(s2); SWAPB(s3); }
  }

  if (s == NSTR - 1) {
    float cs0 = 0.f, cs1 = 0.f, cs2 = 0.f;
    float cm0 = -INFINITY, cm1 = -INFINITY, cm2 = -INFINITY;
    EMITB(s0); EMITB(s1); EMITB(s2); EMITB(s3);
    STORE_CROSS(128);
  }

  // ---- per-channel strip reduction (wave-local, deterministic) ----
#define REDUCE_CH(S, CH) do { \
    float _ss = S.sA, _sm = S.mH; \
    for (int off = 32; off > 0; off >>= 1) { \
      _ss += __shfl_down(_ss, off, 64); \
      _sm = fmaxf(_sm, __shfl_down(_sm, off, 64)); \
    } \
    if (lane == 0) { \
      size_t _bc = (size_t)(b * C_CH + cb + (CH)); \
      psum[_bc * NSTR + s] = _ss; \
      pmax[_bc * NSTR + s] = _sm; \
    } } while(0)

  REDUCE_CH(s0, 0); REDUCE_CH(s1, 1); REDUCE_CH(s2, 2); REDUCE_CH(s3, 3);
}

// -------- Kernel 2: combine group partials -> sa_in -------------------------
__global__ __launch_bounds__(256) void combine_kernel(
    const float* __restrict__ chpsum, const float* __restrict__ chpmax,
    float* __restrict__ sa_in)
{
  int b = blockIdx.y;
  int s = blockIdx.x * 256 + threadIdx.x;
  if (s >= SP) return;
  int jo  = s / WO;
  int col = s - jo * WO;
  size_t off = (size_t)jo * WOP + col;
  float sum = 0.f, mx = -INFINITY;
  #pragma unroll 4
  for (int gg = 0; gg < NGE; ++gg) {
    sum += chpsum[((size_t)(b * NGE + gg)) * (HO * WOP) + off];
    mx = fmaxf(mx, chpmax[((size_t)(b * NGE + gg)) * (HO * WOP) + off]);
  }
  sa_in[(size_t)b * 2 * SP + s]      = sum * (1.f / 256.f);
  sa_in[(size_t)b * 2 * SP + SP + s] = mx;
}

// -------- Kernel 3: channel-attention MLP -----------------------------------
__global__ __launch_bounds__(128) void mlp_kernel(
    const float* __restrict__ psum, const float* __restrict__ pmax,
    const float* __restrict__ w1, const float* __restrict__ b1,
    const float* __restrict__ w2, const float* __restrict__ b2,
    float* __restrict__ att)
{
  int b = blockIdx.x;
  int c = threadIdx.x;   // 128 threads
  __shared__ float p[C_CH];
  __shared__ float h[HIDDEN];

  float s = 0.f, m = -INFINITY;
  #pragma unroll
  for (int k = 0; k < NSTR; ++k) {
    s += psum[(b * C_CH + c) * NSTR + k];
    m = fmaxf(m, pmax[(b * C_CH + c) * NSTR + k]);
  }
  p[c] = s * (1.f / 16641.f) + m;
  __syncthreads();

  if (c < HIDDEN) {
    float acc = b1[c];
    for (int k = 0; k < C_CH; ++k) acc += p[k] * w1[k * HIDDEN + c];
    h[c] = fmaxf(acc, 0.f);
  }
  __syncthreads();

  float acc = b2[c];
  #pragma unroll
  for (int j = 0; j < HIDDEN; ++j) acc += h[j] * w2[j * C_CH + c];
  att[b * C_CH + c] = 1.f / (1.f + expf(-acc));
}

// -------- Kernel 4: 5x5 conv (2->1 ch, zero pad) + sigmoid ------------------
__global__ __launch_bounds__(256) void conv_kernel(
    const float* __restrict__ sa_in, const float* __restrict__ w_sa,
    float* __restrict__ sa)
{
  int b = blockIdx.y;
  int s = blockIdx.x * 256 + threadIdx.x;
  if (s >= SP) return;
  int i = s / WO;
  int j = s - i * WO;
  float acc = 0.f;
  const float* in0 = sa_in + (size_t)b * 2 * SP;
  #pragma unroll
  for (int ch = 0; ch < 2; ++ch) {
    const float* in = in0 + ch * SP;
    #pragma unroll
    for (int u = 0; u < 5; ++u) {
      int ii = i + u - 2;
      if (ii < 0 || ii >= HO) continue;
      #pragma unroll
      for (int v = 0; v < 5; ++v) {
        int jj = j + v - 2;
        if (jj < 0 || jj >= WO) continue;
        acc += in[ii * WO + jj] * w_sa[(ch * 5 + u) * 5 + v];
      }
    }
  }
  sa[(size_t)b * SP + s] = 1.f / (1.f + expf(-acc));
}

// -------- Kernel 4b: bilinear resize sa (8,129,129) -> sar (8,256,256) ------
__global__ __launch_bounds__(256) void resize_kernel(
    const float* __restrict__ sa, float* __restrict__ sar)
{
  int idx = blockIdx.x * 256 + threadIdx.x;   // 8*256*256 = 524288
  int J = idx & 255;
  int I = (idx >> 8) & 255;
  int b = idx >> 16;

  float ti = (I + 0.5f) * (129.f / 256.f) - 0.5f;
  ti = fminf(fmaxf(ti, 0.f), 128.f);
  int i0 = (int)ti;
  float fi = ti - (float)i0;
  int i1 = min(i0 + 1, 128);

  float tj = (J + 0.5f) * (129.f / 256.f) - 0.5f;
  tj = fminf(fmaxf(tj, 0.f), 128.f);
  int jj0 = (int)tj;
  float fj = tj - (float)jj0;
  int jj1 = min(jj0 + 1, 128);

  const float* r0 = sa + ((size_t)b * HO + i0) * WO;
  const float* r1 = sa + ((size_t)b * HO + i1) * WO;
  float v0 = r0[jj0] + fj * (r0[jj1] - r0[jj0]);
  float v1 = r1[jj0] + fj * (r1[jj1] - r1[jj0]);
  sar[idx] = v0 + fi * (v1 - v0);
}

// -------- Kernel 5: out = x * att[b,c] * sar (pure stream) ------------------
__global__ __launch_bounds__(256) void final2_kernel(
    const float* __restrict__ x, const float* __restrict__ att,
    const float* __restrict__ sar, float* __restrict__ out)
{
  // bid = ((b*64 + rg)*4 + cchunk); block: 4 rows x 256 cols x 32 channels
  int bid = blockIdx.x;
  int cchunk = bid & 3;
  int rg  = (bid >> 2) & 63;
  int b   = bid >> 8;
  int t = threadIdx.x;
  int r = t >> 6;          // 0..3
  int col4 = t & 63;
  int I = rg * 4 + r;

  __shared__ float att_s[32];
  if (t < 32) att_s[t] = att[b * C_CH + cchunk * 32 + t];
  __syncthreads();

  float4 sv = reinterpret_cast<const float4*>(sar + ((size_t)b * 256 + I) * 256)[col4];

  size_t base4 = ((size_t)(b * C_CH + cchunk * 32) * 256 + I) * 64 + col4;
  const float4* xp = reinterpret_cast<const float4*>(x);
  float4* op = reinterpret_cast<float4*>(out);
  #pragma unroll 4
  for (int cc = 0; cc < 32; ++cc) {
    float a = att_s[cc];
    float4 xv = xp[base4 + (size_t)cc * 16384];
    float4 ov;
    ov.x = xv.x * a * sv.x;
    ov.y = xv.y * a * sv.y;
    ov.z = xv.z * a * sv.z;
    ov.w = xv.w * a * sv.w;
    op[base4 + (size_t)cc * 16384] = ov;
  }
}

extern "C" void kernel_launch(void* const* d_in, const int* in_sizes, int n_in,
                              void* d_out, int out_size, void* d_ws, size_t ws_size,
                              hipStream_t stream) {
  const float* x    = (const float*)d_in[0];
  const float* w1   = (const float*)d_in[1];
  const float* b1   = (const float*)d_in[2];
  const float* w2   = (const float*)d_in[3];
  const float* b2   = (const float*)d_in[4];
  const float* w_sa = (const float*)d_in[5];
  float* out = (float*)d_out;

  // workspace layout (floats)
  float* chpsum = (float*)d_ws;                            // B*NGE*HO*WOP
  float* chpmax = chpsum + (size_t)B_N * NGE * HO * WOP;   // B*NGE*HO*WOP
  float* psum   = chpmax + (size_t)B_N * NGE * HO * WOP;   // B*C*NSTR
  float* pmax   = psum + B_N * C_CH * NSTR;                // B*C*NSTR
  float* sa_in  = pmax + B_N * C_CH * NSTR;                // B*2*SP
  float* att    = sa_in + (size_t)B_N * 2 * SP;            // B*C
  float* sa     = att + B_N * C_CH;                        // B*SP
  float* sar    = sa + (size_t)B_N * SP;                   // B*256*256

  hipLaunchKernelGGL(dwt_stream_kernel, dim3(B_N * 8 * NSTR), dim3(256), 0, stream,
                     x, psum, pmax, chpsum, chpmax);
  hipLaunchKernelGGL(combine_kernel, dim3((SP + 255) / 256, B_N), dim3(256), 0, stream,
                     chpsum, chpmax, sa_in);
  hipLaunchKernelGGL(mlp_kernel, dim3(B_N), dim3(C_CH), 0, stream,
                     psum, pmax, w1, b1, w2, b2, att);
  hipLaunchKernelGGL(conv_kernel, dim3((SP + 255) / 256, B_N), dim3(256), 0, stream,
                     sa_in, w_sa, sa);
  hipLaunchKernelGGL(resize_kernel, dim3(B_N * H_IN * W_IN / 256), dim3(256), 0, stream,
                     sa, sar);
  hipLaunchKernelGGL(final2_kernel, dim3(B_N * 64 * 4), dim3(256), 0, stream,
                     x, att, sar, out);
}